// Round 1
// baseline (403.242 us; speedup 1.0000x reference)
//
#include <hip/hip_runtime.h>
#include <hip/hip_bf16.h>

// Problem constants
#define Bsz 256
#define Cch 3
#define Him 224
#define Wim 224
#define RET 32
#define NZ 3
#define HG 1024
#define HL 256
#define GDIM 9216          // NZ*Cch*RET*RET
#define NOUT 1280          // HG+HL

// ---------------------------------------------------------------------------
// Foveate: g[b, z, c, i, j]  (B x 9216), fixed-weight bilinear gathers.
// z=0: exact crop; z=1: avg 2x2 at (2i,2j); z=2: avg 2x2 at (4i+1,4j+1).
// ---------------------------------------------------------------------------
__global__ __launch_bounds__(256) void foveate_kernel(
    const float* __restrict__ img, const float* __restrict__ loc,
    float* __restrict__ g) {
  int idx = blockIdx.x * 256 + threadIdx.x;          // < 256*9216
  int b  = idx / GDIM;
  int r  = idx - b * GDIM;
  int z  = r / (Cch * RET * RET);
  int r2 = r - z * (Cch * RET * RET);
  int c  = r2 / (RET * RET);
  int p  = r2 - c * (RET * RET);
  int i  = p >> 5, j = p & 31;

  float dr = (loc[b * 2 + 0] + 1.0f) * 0.5f * (float)Wim;
  float dc = (loc[b * 2 + 1] + 1.0f) * 0.5f * (float)Wim;
  int half = 16 << z;
  int top  = (int)truncf(dr - (float)half);
  int left = (int)truncf(dc - (float)half);

  const float* base = img + ((long)b * Cch + c) * (Him * Wim);
  float v;
  if (z == 0) {
    v = base[(top + i) * Wim + left + j];
  } else {
    int rr, cc;
    if (z == 1) { rr = top + 2 * i;     cc = left + 2 * j;     }
    else        { rr = top + 4 * i + 1; cc = left + 4 * j + 1; }
    v = 0.25f * (base[rr * Wim + cc] + base[rr * Wim + cc + 1] +
                 base[(rr + 1) * Wim + cc] + base[(rr + 1) * Wim + cc + 1]);
  }
  g[idx] = v;
}

// ---------------------------------------------------------------------------
// Generic 64x64 fp32 GEMM tile, BK=16, 256 threads, 4x4 microtile.
// As stored K-major [16][68] (pad->16B-aligned b128 reads), Bs [16][64].
// ---------------------------------------------------------------------------
#define AS_LD 68
__device__ __forceinline__ void gemm64x64(
    const float* __restrict__ A, int lda,
    const float* __restrict__ Bm, int ldb,
    int m0, int n0, int kbase, int klen,
    float acc[4][4], float* lds) {
  float* As = lds;                 // 16 * 68
  float* Bs = lds + 16 * AS_LD;    // 16 * 64
  const int t   = threadIdx.x;
  const int ar  = t >> 2, ac4 = (t & 3) * 4;     // A stage: row 0..63, col*4
  const int br  = t >> 4, bc4 = (t & 15) * 4;    // B stage: row 0..15, col*4
  const int ty  = t >> 4, tx  = t & 15;          // compute layout 16x16

  const float* Aptr = A + (long)(m0 + ar) * lda + kbase + ac4;
  const float* Bptr = Bm + (long)(kbase + br) * ldb + n0 + bc4;

  for (int kk = 0; kk < klen; kk += 16) {
    const float4 av = *(const float4*)(Aptr + kk);
    const float4 bv = *(const float4*)(Bptr + (long)kk * ldb);
    __syncthreads();   // previous iter's LDS reads done
    As[(ac4 + 0) * AS_LD + ar] = av.x;
    As[(ac4 + 1) * AS_LD + ar] = av.y;
    As[(ac4 + 2) * AS_LD + ar] = av.z;
    As[(ac4 + 3) * AS_LD + ar] = av.w;
    *(float4*)&Bs[br * 64 + bc4] = bv;
    __syncthreads();
#pragma unroll
    for (int k = 0; k < 16; ++k) {
      float4 a4 = *(const float4*)&As[k * AS_LD + ty * 4];
      float4 b4 = *(const float4*)&Bs[k * 64 + tx * 4];
      acc[0][0] = fmaf(a4.x, b4.x, acc[0][0]);
      acc[0][1] = fmaf(a4.x, b4.y, acc[0][1]);
      acc[0][2] = fmaf(a4.x, b4.z, acc[0][2]);
      acc[0][3] = fmaf(a4.x, b4.w, acc[0][3]);
      acc[1][0] = fmaf(a4.y, b4.x, acc[1][0]);
      acc[1][1] = fmaf(a4.y, b4.y, acc[1][1]);
      acc[1][2] = fmaf(a4.y, b4.z, acc[1][2]);
      acc[1][3] = fmaf(a4.y, b4.w, acc[1][3]);
      acc[2][0] = fmaf(a4.z, b4.x, acc[2][0]);
      acc[2][1] = fmaf(a4.z, b4.y, acc[2][1]);
      acc[2][2] = fmaf(a4.z, b4.z, acc[2][2]);
      acc[2][3] = fmaf(a4.z, b4.w, acc[2][3]);
      acc[3][0] = fmaf(a4.w, b4.x, acc[3][0]);
      acc[3][1] = fmaf(a4.w, b4.y, acc[3][1]);
      acc[3][2] = fmaf(a4.w, b4.z, acc[3][2]);
      acc[3][3] = fmaf(a4.w, b4.w, acc[3][3]);
    }
  }
}

// gemm1: partials[z][256][1024] = g(64x64 tile) @ W1, split-K=4 (chunks of 2304)
__global__ __launch_bounds__(256) void gemm1_kernel(
    const float* __restrict__ g, const float* __restrict__ W1,
    float* __restrict__ P) {
  __shared__ float lds[16 * AS_LD + 16 * 64];
  float acc[4][4] = {};
  const int n0 = blockIdx.x * 64, m0 = blockIdx.y * 64, z = blockIdx.z;
  gemm64x64(g, GDIM, W1, HG, m0, n0, z * 2304, 2304, acc, lds);
  float* Pz = P + (long)z * Bsz * HG;
  const int ty = threadIdx.x >> 4, tx = threadIdx.x & 15;
#pragma unroll
  for (int i = 0; i < 4; ++i) {
    *(float4*)&Pz[(m0 + ty * 4 + i) * HG + n0 + tx * 4] =
        make_float4(acc[i][0], acc[i][1], acc[i][2], acc[i][3]);
  }
}

// reduce1: h1 = relu(b1 + sum_z partials)
__global__ __launch_bounds__(256) void reduce1_kernel(
    const float* __restrict__ P, const float* __restrict__ b1,
    float* __restrict__ h1) {
  int idx = blockIdx.x * 256 + threadIdx.x;  // < 262144
  int n = idx & (HG - 1);
  const int S = Bsz * HG;
  float s = b1[n] + P[idx] + P[idx + S] + P[idx + 2 * S] + P[idx + 3 * S];
  h1[idx] = fmaxf(s, 0.0f);
}

// h2 = relu(loc @ W2 + b2)   (256 x 256, K=2)
__global__ __launch_bounds__(256) void h2_kernel(
    const float* __restrict__ loc, const float* __restrict__ W2,
    const float* __restrict__ b2, float* __restrict__ h2) {
  int b = blockIdx.x, n = threadIdx.x;
  float l0 = loc[b * 2 + 0], l1 = loc[b * 2 + 1];
  float s = fmaf(l0, W2[n], fmaf(l1, W2[HL + n], b2[n]));
  h2[b * HL + n] = fmaxf(s, 0.0f);
}

// gemm2: z<4 -> partial of h1@W3 (K chunk z*256..), z==4 -> h2@W4 (K=256)
__global__ __launch_bounds__(256) void gemm2_kernel(
    const float* __restrict__ h1, const float* __restrict__ W3,
    const float* __restrict__ h2, const float* __restrict__ W4,
    float* __restrict__ P) {
  __shared__ float lds[16 * AS_LD + 16 * 64];
  float acc[4][4] = {};
  const int n0 = blockIdx.x * 64, m0 = blockIdx.y * 64, z = blockIdx.z;
  if (z < 4) gemm64x64(h1, HG, W3, NOUT, m0, n0, z * 256, 256, acc, lds);
  else       gemm64x64(h2, HL, W4, NOUT, m0, n0, 0,       256, acc, lds);
  float* Pz = P + (long)z * Bsz * NOUT;
  const int ty = threadIdx.x >> 4, tx = threadIdx.x & 15;
#pragma unroll
  for (int i = 0; i < 4; ++i) {
    *(float4*)&Pz[(m0 + ty * 4 + i) * NOUT + n0 + tx * 4] =
        make_float4(acc[i][0], acc[i][1], acc[i][2], acc[i][3]);
  }
}

// reduce2: out = relu(relu(b3 + sum_{z<4} P2) + relu(b4 + P2[4]))
__global__ __launch_bounds__(256) void reduce2_kernel(
    const float* __restrict__ P, const float* __restrict__ b3,
    const float* __restrict__ b4, float* __restrict__ out) {
  int idx = blockIdx.x * 256 + threadIdx.x;  // < 327680
  int n = idx % NOUT;
  const int S = Bsz * NOUT;
  float a = b3[n] + P[idx] + P[idx + S] + P[idx + 2 * S] + P[idx + 3 * S];
  float c = b4[n] + P[idx + 4 * S];
  out[idx] = fmaxf(fmaxf(a, 0.0f) + fmaxf(c, 0.0f), 0.0f);
}

extern "C" void kernel_launch(void* const* d_in, const int* in_sizes, int n_in,
                              void* d_out, int out_size, void* d_ws, size_t ws_size,
                              hipStream_t stream) {
  const float* images = (const float*)d_in[0];
  const float* locs   = (const float*)d_in[1];
  const float* W1 = (const float*)d_in[2];
  const float* b1 = (const float*)d_in[3];
  const float* W2 = (const float*)d_in[4];
  const float* b2 = (const float*)d_in[5];
  const float* W3 = (const float*)d_in[6];
  const float* b3 = (const float*)d_in[7];
  const float* W4 = (const float*)d_in[8];
  const float* b4 = (const float*)d_in[9];
  float* out = (float*)d_out;

  float* ws = (float*)d_ws;
  float* g   = ws;                         // 256*9216    = 2,359,296
  float* P1  = g + (long)Bsz * GDIM;       // 4*256*1024  = 1,048,576
  float* h1  = P1 + 4L * Bsz * HG;         // 256*1024    =   262,144
  float* h2  = h1 + (long)Bsz * HG;        // 256*256     =    65,536
  float* P2  = h2 + (long)Bsz * HL;        // 5*256*1280  = 1,638,400

  foveate_kernel<<<(Bsz * GDIM) / 256, 256, 0, stream>>>(images, locs, g);
  gemm1_kernel<<<dim3(HG / 64, Bsz / 64, 4), 256, 0, stream>>>(g, W1, P1);
  reduce1_kernel<<<(Bsz * HG) / 256, 256, 0, stream>>>(P1, b1, h1);
  h2_kernel<<<Bsz, HL, 0, stream>>>(locs, W2, b2, h2);
  gemm2_kernel<<<dim3(NOUT / 64, Bsz / 64, 5), 256, 0, stream>>>(h1, W3, h2, W4, P2);
  reduce2_kernel<<<(Bsz * NOUT) / 256, 256, 0, stream>>>(P2, b3, b4, out);
}

// Round 2
// 299.008 us; speedup vs baseline: 1.3486x; 1.3486x over previous
//
#include <hip/hip_runtime.h>

typedef __attribute__((ext_vector_type(8))) short short8;
typedef __attribute__((ext_vector_type(4))) float f32x4;

#define Bsz 256
#define Cch 3
#define Him 224
#define Wim 224
#define RET 32
#define HG 1024
#define HL 256
#define GDIM 9216
#define NOUT 1280

__device__ __forceinline__ unsigned short f2bf(float x) {
  unsigned u = __float_as_uint(x);
  unsigned r = (u + 0x7fffu + ((u >> 16) & 1u)) >> 16;
  return (unsigned short)r;
}
__device__ __forceinline__ float bf2f(unsigned short h) {
  return __uint_as_float((unsigned)h << 16);
}

// ---------------------------------------------------------------------------
// Foveate -> bf16 hi/lo planes g[256][9216]
// ---------------------------------------------------------------------------
__global__ __launch_bounds__(256) void foveate_kernel(
    const float* __restrict__ img, const float* __restrict__ loc,
    unsigned short* __restrict__ ghi, unsigned short* __restrict__ glo) {
  int idx = blockIdx.x * 256 + threadIdx.x;
  int b = idx / GDIM;
  int r = idx - b * GDIM;
  int z = r / (Cch * RET * RET);
  int r2 = r - z * (Cch * RET * RET);
  int c = r2 / (RET * RET);
  int p = r2 - c * (RET * RET);
  int i = p >> 5, j = p & 31;
  float dr = (loc[b * 2 + 0] + 1.f) * .5f * (float)Wim;
  float dc = (loc[b * 2 + 1] + 1.f) * .5f * (float)Wim;
  int half = 16 << z;
  int top = (int)truncf(dr - (float)half), left = (int)truncf(dc - (float)half);
  const float* base = img + ((long)b * Cch + c) * (Him * Wim);
  float v;
  if (z == 0) {
    v = base[(top + i) * Wim + left + j];
  } else {
    int rr = (z == 1) ? top + 2 * i : top + 4 * i + 1;
    int cc = (z == 1) ? left + 2 * j : left + 4 * j + 1;
    v = .25f * (base[rr * Wim + cc] + base[rr * Wim + cc + 1] +
                base[(rr + 1) * Wim + cc] + base[(rr + 1) * Wim + cc + 1]);
  }
  unsigned short h = f2bf(v);
  ghi[idx] = h;
  glo[idx] = f2bf(v - bf2f(h));
}

// ---------------------------------------------------------------------------
// Transpose + split: in[K][N] fp32 -> outHi/outLo [N][K] bf16
// ---------------------------------------------------------------------------
__global__ __launch_bounds__(256) void tconv_kernel(
    const float* __restrict__ in, unsigned short* __restrict__ oh,
    unsigned short* __restrict__ ol, int K, int N) {
  __shared__ float tile[32][33];
  int n0 = blockIdx.x * 32, k0 = blockIdx.y * 32;
  int r = threadIdx.x >> 3, c4 = (threadIdx.x & 7) * 4;
  float4 v = *(const float4*)(in + (long)(k0 + r) * N + n0 + c4);
  tile[r][c4 + 0] = v.x; tile[r][c4 + 1] = v.y;
  tile[r][c4 + 2] = v.z; tile[r][c4 + 3] = v.w;
  __syncthreads();
  float x0 = tile[c4 + 0][r], x1 = tile[c4 + 1][r];
  float x2 = tile[c4 + 2][r], x3 = tile[c4 + 3][r];
  unsigned short h0 = f2bf(x0), h1 = f2bf(x1), h2 = f2bf(x2), h3 = f2bf(x3);
  long o = (long)(n0 + r) * K + k0 + c4;
  *(ushort4*)(oh + o) = make_ushort4(h0, h1, h2, h3);
  *(ushort4*)(ol + o) = make_ushort4(f2bf(x0 - bf2f(h0)), f2bf(x1 - bf2f(h1)),
                                     f2bf(x2 - bf2f(h2)), f2bf(x3 - bf2f(h3)));
}

// ---------------------------------------------------------------------------
// MFMA bf16x3 tile: block 128x128, 4 waves of 64x64, BK=32.
// LDS planes in fragment-linear layout [rf][lane][8] so every ds_read_b128 is
// wave-contiguous (conflict-free). A-layout (verified): m=lane&15,
// k=(lane>>4)*8+j.  C/D: col=lane&15, row=(lane>>4)*4+reg.
// ---------------------------------------------------------------------------
__device__ __forceinline__ void mfma_tile(
    const unsigned short* __restrict__ Ahi, const unsigned short* __restrict__ Alo, int lda,
    const unsigned short* __restrict__ Bhi, const unsigned short* __restrict__ Blo, int ldb,
    int m0, int n0, int kb, int iters, f32x4 acc[4][4], unsigned short* lds) {
  const int t = threadIdx.x;
  const int lane = t & 63;
  const int wm = (t >> 7) & 1, wn = (t >> 6) & 1;
  unsigned short* pAh = lds;
  unsigned short* pAl = lds + 4096;
  unsigned short* pBh = lds + 8192;
  unsigned short* pBl = lds + 12288;
  const int c0 = t, c1 = t + 256;
  const int r0 = c0 >> 2, ko0 = c0 & 3;
  const int r1 = c1 >> 2, ko1 = c1 & 3;
  const long a0 = (long)(m0 + r0) * lda + kb + ko0 * 8;
  const long a1 = (long)(m0 + r1) * lda + kb + ko1 * 8;
  const long b0 = (long)(n0 + r0) * ldb + kb + ko0 * 8;
  const long b1 = (long)(n0 + r1) * ldb + kb + ko1 * 8;
  const int d0 = ((r0 >> 4) * 64 + (r0 & 15) + ko0 * 16) * 8;
  const int d1 = ((r1 >> 4) * 64 + (r1 & 15) + ko1 * 16) * 8;

  for (int it = 0; it < iters; ++it) {
    const long ka = (long)it * 32;
    uint4 vah0 = *(const uint4*)(Ahi + a0 + ka);
    uint4 vah1 = *(const uint4*)(Ahi + a1 + ka);
    uint4 val0 = *(const uint4*)(Alo + a0 + ka);
    uint4 val1 = *(const uint4*)(Alo + a1 + ka);
    uint4 vbh0 = *(const uint4*)(Bhi + b0 + ka);
    uint4 vbh1 = *(const uint4*)(Bhi + b1 + ka);
    uint4 vbl0 = *(const uint4*)(Blo + b0 + ka);
    uint4 vbl1 = *(const uint4*)(Blo + b1 + ka);
    __syncthreads();
    *(uint4*)(pAh + d0) = vah0; *(uint4*)(pAh + d1) = vah1;
    *(uint4*)(pAl + d0) = val0; *(uint4*)(pAl + d1) = val1;
    *(uint4*)(pBh + d0) = vbh0; *(uint4*)(pBh + d1) = vbh1;
    *(uint4*)(pBl + d0) = vbl0; *(uint4*)(pBl + d1) = vbl1;
    __syncthreads();
    short8 ah[4], al[4], bh[4], bl[4];
#pragma unroll
    for (int f = 0; f < 4; ++f) {
      int ra = ((wm * 4 + f) * 64 + lane) * 8;
      int rb = ((wn * 4 + f) * 64 + lane) * 8;
      ah[f] = *(const short8*)(pAh + ra);
      al[f] = *(const short8*)(pAl + ra);
      bh[f] = *(const short8*)(pBh + rb);
      bl[f] = *(const short8*)(pBl + rb);
    }
#pragma unroll
    for (int mf = 0; mf < 4; ++mf)
#pragma unroll
      for (int nf = 0; nf < 4; ++nf) {
        acc[mf][nf] = __builtin_amdgcn_mfma_f32_16x16x32_bf16(ah[mf], bh[nf], acc[mf][nf], 0, 0, 0);
        acc[mf][nf] = __builtin_amdgcn_mfma_f32_16x16x32_bf16(ah[mf], bl[nf], acc[mf][nf], 0, 0, 0);
        acc[mf][nf] = __builtin_amdgcn_mfma_f32_16x16x32_bf16(al[mf], bh[nf], acc[mf][nf], 0, 0, 0);
      }
  }
}

__device__ __forceinline__ void epilogue(float* __restrict__ Pz, int ldp, int m0, int n0,
                                         f32x4 acc[4][4]) {
  const int t = threadIdx.x, lane = t & 63;
  const int wm = (t >> 7) & 1, wn = (t >> 6) & 1;
  const int rbase = (lane >> 4) * 4, col = lane & 15;
#pragma unroll
  for (int mf = 0; mf < 4; ++mf)
#pragma unroll
    for (int nf = 0; nf < 4; ++nf) {
      int row = m0 + wm * 64 + mf * 16 + rbase;
      int cc = n0 + wn * 64 + nf * 16 + col;
#pragma unroll
      for (int r = 0; r < 4; ++r)
        Pz[(long)(row + r) * ldp + cc] = acc[mf][nf][r];
    }
}

// gemm1: P[z][256][1024] = g @ W1 chunk, splitK=32 (chunk 288 = 9 iters of 32)
__global__ __launch_bounds__(256, 2) void gemm1_kernel(
    const unsigned short* __restrict__ ghi, const unsigned short* __restrict__ glo,
    const unsigned short* __restrict__ w1thi, const unsigned short* __restrict__ w1tlo,
    float* __restrict__ P) {
  __shared__ __align__(16) unsigned short lds[16384];
  f32x4 zz = {0.f, 0.f, 0.f, 0.f};
  f32x4 acc[4][4];
  for (int i = 0; i < 4; ++i) for (int j = 0; j < 4; ++j) acc[i][j] = zz;
  int n0 = blockIdx.x * 128, m0 = blockIdx.y * 128, z = blockIdx.z;
  mfma_tile(ghi, glo, GDIM, w1thi, w1tlo, GDIM, m0, n0, z * 288, 9, acc, lds);
  epilogue(P + (long)z * Bsz * HG, HG, m0, n0, acc);
}

// gemm2: z<8 -> h1@W3 chunk (K=128 each); z==8 -> h2@W4 (K=256)
__global__ __launch_bounds__(256, 2) void gemm2_kernel(
    const unsigned short* __restrict__ h1hi, const unsigned short* __restrict__ h1lo,
    const unsigned short* __restrict__ h2hi, const unsigned short* __restrict__ h2lo,
    const unsigned short* __restrict__ w3thi, const unsigned short* __restrict__ w3tlo,
    const unsigned short* __restrict__ w4thi, const unsigned short* __restrict__ w4tlo,
    float* __restrict__ P) {
  __shared__ __align__(16) unsigned short lds[16384];
  f32x4 zz = {0.f, 0.f, 0.f, 0.f};
  f32x4 acc[4][4];
  for (int i = 0; i < 4; ++i) for (int j = 0; j < 4; ++j) acc[i][j] = zz;
  int n0 = blockIdx.x * 128, m0 = blockIdx.y * 128, z = blockIdx.z;
  if (z < 8)
    mfma_tile(h1hi, h1lo, HG, w3thi, w3tlo, HG, m0, n0, z * 128, 4, acc, lds);
  else
    mfma_tile(h2hi, h2lo, HL, w4thi, w4tlo, HL, m0, n0, 0, 8, acc, lds);
  epilogue(P + (long)z * Bsz * NOUT, NOUT, m0, n0, acc);
}

// reduce1: h1 = relu(b1 + sum_{z<32} P1[z]) -> bf16 hi/lo
__global__ __launch_bounds__(256) void reduce1_kernel(
    const float* __restrict__ P, const float* __restrict__ b1,
    unsigned short* __restrict__ h1hi, unsigned short* __restrict__ h1lo) {
  int i4 = (blockIdx.x * 256 + threadIdx.x) * 4;
  float4 s = *(const float4*)(P + i4);
  for (int z = 1; z < 32; ++z) {
    float4 p = *(const float4*)(P + (long)z * (Bsz * HG) + i4);
    s.x += p.x; s.y += p.y; s.z += p.z; s.w += p.w;
  }
  int n = i4 & (HG - 1);
  float4 bb = *(const float4*)(b1 + n);
  float v0 = fmaxf(s.x + bb.x, 0.f), v1 = fmaxf(s.y + bb.y, 0.f);
  float v2 = fmaxf(s.z + bb.z, 0.f), v3 = fmaxf(s.w + bb.w, 0.f);
  unsigned short h0 = f2bf(v0), h1 = f2bf(v1), h2 = f2bf(v2), h3 = f2bf(v3);
  *(ushort4*)(h1hi + i4) = make_ushort4(h0, h1, h2, h3);
  *(ushort4*)(h1lo + i4) = make_ushort4(f2bf(v0 - bf2f(h0)), f2bf(v1 - bf2f(h1)),
                                        f2bf(v2 - bf2f(h2)), f2bf(v3 - bf2f(h3)));
}

// h2 = relu(loc @ W2 + b2) -> bf16 hi/lo
__global__ __launch_bounds__(256) void h2_kernel(
    const float* __restrict__ loc, const float* __restrict__ W2,
    const float* __restrict__ b2, unsigned short* __restrict__ h2hi,
    unsigned short* __restrict__ h2lo) {
  int b = blockIdx.x, n = threadIdx.x;
  float s = fmaf(loc[b * 2], W2[n], fmaf(loc[b * 2 + 1], W2[HL + n], b2[n]));
  s = fmaxf(s, 0.f);
  unsigned short h = f2bf(s);
  h2hi[b * HL + n] = h;
  h2lo[b * HL + n] = f2bf(s - bf2f(h));
}

// reduce2: out = relu(relu(b3 + sum_{z<8} P2) + relu(b4 + P2[8]))
__global__ __launch_bounds__(256) void reduce2_kernel(
    const float* __restrict__ P, const float* __restrict__ b3,
    const float* __restrict__ b4, float* __restrict__ out) {
  int i4 = (blockIdx.x * 256 + threadIdx.x) * 4;
  float4 a = *(const float4*)(P + i4);
  for (int z = 1; z < 8; ++z) {
    float4 p = *(const float4*)(P + (long)z * (Bsz * NOUT) + i4);
    a.x += p.x; a.y += p.y; a.z += p.z; a.w += p.w;
  }
  float4 c = *(const float4*)(P + 8L * (Bsz * NOUT) + i4);
  int n = i4 % NOUT;
  float4 b3v = *(const float4*)(b3 + n);
  float4 b4v = *(const float4*)(b4 + n);
  float4 o;
  o.x = fmaxf(fmaxf(a.x + b3v.x, 0.f) + fmaxf(c.x + b4v.x, 0.f), 0.f);
  o.y = fmaxf(fmaxf(a.y + b3v.y, 0.f) + fmaxf(c.y + b4v.y, 0.f), 0.f);
  o.z = fmaxf(fmaxf(a.z + b3v.z, 0.f) + fmaxf(c.z + b4v.z, 0.f), 0.f);
  o.w = fmaxf(fmaxf(a.w + b3v.w, 0.f) + fmaxf(c.w + b4v.w, 0.f), 0.f);
  *(float4*)(out + i4) = o;
}

extern "C" void kernel_launch(void* const* d_in, const int* in_sizes, int n_in,
                              void* d_out, int out_size, void* d_ws, size_t ws_size,
                              hipStream_t stream) {
  const float* images = (const float*)d_in[0];
  const float* locs = (const float*)d_in[1];
  const float* W1 = (const float*)d_in[2];
  const float* b1 = (const float*)d_in[3];
  const float* W2 = (const float*)d_in[4];
  const float* b2 = (const float*)d_in[5];
  const float* W3 = (const float*)d_in[6];
  const float* b3 = (const float*)d_in[7];
  const float* W4 = (const float*)d_in[8];
  const float* b4 = (const float*)d_in[9];
  float* out = (float*)d_out;

  unsigned short* ghi = (unsigned short*)d_ws;
  unsigned short* glo = ghi + (long)Bsz * GDIM;
  unsigned short* w1thi = glo + (long)Bsz * GDIM;
  unsigned short* w1tlo = w1thi + (long)GDIM * HG;
  unsigned short* w3thi = w1tlo + (long)GDIM * HG;
  unsigned short* w3tlo = w3thi + (long)HG * NOUT;
  unsigned short* w4thi = w3tlo + (long)HG * NOUT;
  unsigned short* w4tlo = w4thi + (long)HL * NOUT;
  unsigned short* h1hi = w4tlo + (long)HL * NOUT;
  unsigned short* h1lo = h1hi + (long)Bsz * HG;
  unsigned short* h2hi = h1lo + (long)Bsz * HG;
  unsigned short* h2lo = h2hi + (long)Bsz * HL;
  float* P1 = (float*)(h2lo + (long)Bsz * HL);  // 32*256*1024 fp32
  float* P2 = P1;                               // alias: P1 consumed before gemm2

  tconv_kernel<<<dim3(HG / 32, GDIM / 32), 256, 0, stream>>>(W1, w1thi, w1tlo, GDIM, HG);
  tconv_kernel<<<dim3(NOUT / 32, HG / 32), 256, 0, stream>>>(W3, w3thi, w3tlo, HG, NOUT);
  tconv_kernel<<<dim3(NOUT / 32, HL / 32), 256, 0, stream>>>(W4, w4thi, w4tlo, HL, NOUT);
  foveate_kernel<<<(Bsz * GDIM) / 256, 256, 0, stream>>>(images, locs, ghi, glo);
  gemm1_kernel<<<dim3(HG / 128, Bsz / 128, 32), 256, 0, stream>>>(ghi, glo, w1thi, w1tlo, P1);
  reduce1_kernel<<<(Bsz * HG) / 1024, 256, 0, stream>>>(P1, b1, h1hi, h1lo);
  h2_kernel<<<Bsz, HL, 0, stream>>>(locs, W2, b2, h2hi, h2lo);
  gemm2_kernel<<<dim3(NOUT / 128, Bsz / 128, 9), 256, 0, stream>>>(
      h1hi, h1lo, h2hi, h2lo, w3thi, w3tlo, w4thi, w4tlo, P2);
  reduce2_kernel<<<(Bsz * NOUT) / 1024, 256, 0, stream>>>(P2, b3, b4, out);
}